// Round 17
// baseline (198.226 us; speedup 1.0000x reference)
//
#include <hip/hip_runtime.h>
#include <math.h>
#include <type_traits>

#define BH 4
#define HH 128
#define WW 128
#define HW (HH * WW)
#define SSTR 600   // dcn LDS row stride in shorts (1200B)

typedef __attribute__((ext_vector_type(8))) short bf16x8;
typedef __attribute__((ext_vector_type(4))) float f32x4;
typedef unsigned uint4a __attribute__((ext_vector_type(4), aligned(4)));

__device__ inline short f2bf(float f) {
    union { float f; unsigned u; } x; x.f = f;
    unsigned r = x.u + 0x7fff + ((x.u >> 16) & 1);   // RNE
    return (short)(r >> 16);
}
__device__ inline float bf2f(short h) {
    union { unsigned u; float f; } x; x.u = ((unsigned)(unsigned short)h) << 16;
    return x.f;
}
__device__ inline float bflo(unsigned u) {
    union { unsigned u; float f; } x; x.u = u << 16; return x.f;
}
__device__ inline float bfhi(unsigned u) {
    union { unsigned u; float f; } x; x.u = u & 0xffff0000u; return x.f;
}

// ---------------------------------------------------------------------------
// Unified weight repack: jobs 0-3 generic conv weights, job 4 = deform wt.
// ---------------------------------------------------------------------------
struct RepackArgs {
    const float* w[5];
    short* dst[5];
    int off[6];
};

__device__ inline void repack_generic(const float* w, short* dst, int g,
                                      int M, int Cin, int T, int MT)
{
    int lane = g & 63;
    int f = g >> 6;
    int mt = f % MT;
    int kt = f / MT;
    int tap = kt % T;
    int kc = kt / T;
    int m = mt * 16 + (lane & 15);
    int ic0 = kc * 32 + (lane >> 4) * 8;
    short v[8];
#pragma unroll
    for (int i = 0; i < 8; ++i) {
        int ic = ic0 + i;
        float x = (m < M && ic < Cin) ? w[((size_t)m * Cin + ic) * T + tap] : 0.f;
        v[i] = f2bf(x);
    }
    *(bf16x8*)(dst + (size_t)g * 8) = *(const bf16x8*)v;
}

__global__ __launch_bounds__(256) void repack_all_k(RepackArgs a)
{
    int g = blockIdx.x * 256 + threadIdx.x;
    if (g < a.off[1]) {
        repack_generic(a.w[0], a.dst[0], g - a.off[0], 64, 130, 9, 4);
    } else if (g < a.off[2]) {
        repack_generic(a.w[1], a.dst[1], g - a.off[1], 64, 64, 9, 4);
    } else if (g < a.off[3]) {
        repack_generic(a.w[2], a.dst[2], g - a.off[2], 64, 64, 9, 4);
    } else if (g < a.off[4]) {
        repack_generic(a.w[3], a.dst[3], g - a.off[3], 432, 64, 9, 27);
    } else if (g < a.off[5]) {
        int gg = g - a.off[4];
        int lane = gg & 63;
        int f = gg >> 6;
        int mt = f & 3, kc = f >> 2;
        int m = mt * 16 + (lane & 15);
        int ck0 = kc * 32 + (lane >> 4) * 8;
        short v[8];
#pragma unroll
        for (int i = 0; i < 8; ++i) {
            int ck = ck0 + i;                     // < 576
            int dg = ck / 36, rem = ck % 36;
            int k = rem >> 2, cg = rem & 3;
            int c = dg * 4 + cg;
            v[i] = f2bf(a.w[4][((size_t)m * 64 + c) * 9 + k]);
        }
        *(bf16x8*)(a.dst[4] + (size_t)gg * 8) = *(const bf16x8*)v;
    }
}

// ---------------------------------------------------------------------------
// Merged prep: z<BH -> build NHWC concat buffer [B][HW][144];
//              z>=BH -> x NCHW f32 -> dg-major bf16 xt[B][16][HW][4].
// ---------------------------------------------------------------------------
__global__ __launch_bounds__(256) void prep_k(
    const float* __restrict__ xfw, const float* __restrict__ xcur,
    const float* __restrict__ flow, const float* __restrict__ x,
    short* __restrict__ cc, short* __restrict__ xt)
{
    int tid = threadIdx.x;
    int z = blockIdx.z;
    int px = blockIdx.x * 256 + tid;
    if (z < BH) {
        int b = z;
        const float* s0 = xfw + (size_t)b * 64 * HW + px;
        const float* s1 = xcur + (size_t)b * 64 * HW + px;
        const float* s2 = flow + (size_t)b * 2 * HW + px;
        short v[144];
#pragma unroll
        for (int c = 0; c < 64; ++c) v[c] = f2bf(s0[(size_t)c * HW]);
#pragma unroll
        for (int c = 0; c < 64; ++c) v[64 + c] = f2bf(s1[(size_t)c * HW]);
        v[128] = f2bf(s2[0]);
        v[129] = f2bf(s2[HW]);
#pragma unroll
        for (int c = 130; c < 144; ++c) v[c] = 0;
        short* dst = cc + ((size_t)b * HW + px) * 144;
#pragma unroll
        for (int q = 0; q < 18; ++q)
            *(bf16x8*)(dst + q * 8) = *(const bf16x8*)&v[q * 8];
    } else {
        int b = z - BH;
        const float* src = x + (size_t)b * 64 * HW + px;
        short v[64];
#pragma unroll
        for (int c = 0; c < 64; ++c) v[c] = f2bf(src[(size_t)c * HW]);
        short* dstb = xt + (size_t)b * 16 * HW * 4 + (size_t)px * 4;
#pragma unroll
        for (int d = 0; d < 16; ++d)
            *(uint2*)(dstb + (size_t)d * HW * 4) = *(const uint2*)&v[d * 4];
    }
}

// ---------------------------------------------------------------------------
// Implicit-GEMM 3x3 conv, NHWC bf16 in, mfma_f32_16x16x32_bf16.
// 256 thr / 4 waves. Wave tiling: nWn = 4/NTW n-wave groups, nWm = 4/nWn
// m-wave groups. Each wave computes MTW m-tiles x NTW n-tiles -> per tap
// MTW a-loads + NTW b-reads feed MTW*NTW MFMAs. NTW=2 halves LDS b-read
// traffic per MFMA vs NTW=4 (conv1-3 are LDS-read bound).
// QMAJ (conv4): block-local pair/mask layout for dcn.
// ---------------------------------------------------------------------------
template<int CSTR, int KC, bool ACT, int MTW, int NTW, bool QMAJ>
__global__ __launch_bounds__(256) void conv_mfma_k(
    const short* __restrict__ in, const short* __restrict__ wp,
    const float* __restrict__ bias, short* __restrict__ out,
    unsigned* __restrict__ outp, short* __restrict__ outm,
    int Cout, int MB, int MT)
{
    __shared__ alignas(16) short X[3 * 66 * 40];
    const int tid = threadIdx.x;
    const int lane = tid & 63, wv = tid >> 6;
    constexpr int nWn = 4 / NTW;            // 1 or 2
    constexpr int WNS = (nWn == 2) ? 1 : 0;
    constexpr int nWm = 4 / nWn;            // 4 or 2
    const int wn = wv & (nWn - 1);
    const int wm = wv >> WNS;
    const int x0 = blockIdx.x * 64, y = blockIdx.y;
    const int zb = blockIdx.z;
    const int b = zb / MB, mb = zb % MB;

    int mtg[MTW];
#pragma unroll
    for (int mt = 0; mt < MTW; ++mt) {
        int t = (mb * nWm + wm) * MTW + mt;
        mtg[mt] = (t < MT) ? t : MT - 1;      // clamp loads; stores masked
    }

    const int r = tid / 66, c = tid - r * 66;
    const int yy = y + r - 1, xx = x0 + c - 1;
    const bool inb = (tid < 198) && (yy >= 0 && yy < HH && xx >= 0 && xx < WW);
    const short* srcp = in + ((size_t)b * HW + (size_t)yy * WW + xx) * CSTR;
    short* dstp = &X[(r * 66 + c) * 40];

    f32x4 acc[MTW][NTW] = {};

    for (int kc = 0; kc < KC; ++kc) {
        __syncthreads();
        if (tid < 198) {
            if (inb) {
                const short* s0 = srcp + kc * 32;
#pragma unroll
                for (int g = 0; g < 4; ++g)
                    *(bf16x8*)&dstp[g * 8] = *(const bf16x8*)&s0[g * 8];
            } else {
                bf16x8 z = {};
#pragma unroll
                for (int g = 0; g < 4; ++g) *(bf16x8*)&dstp[g * 8] = z;
            }
        }
        __syncthreads();
#pragma unroll
        for (int tap = 0; tap < 9; ++tap) {
            const int dy = tap / 3, dx = tap - dy * 3;
            bf16x8 a[MTW];
#pragma unroll
            for (int mt = 0; mt < MTW; ++mt)
                a[mt] = *(const bf16x8*)(wp + (((size_t)(kc * 9 + tap) * MT + mtg[mt]) * 64 + lane) * 8);
#pragma unroll
            for (int nt = 0; nt < NTW; ++nt) {
                int cc2 = (wn * NTW + nt) * 16 + (lane & 15) + dx;
                bf16x8 bb = *(const bf16x8*)&X[(dy * 66 + cc2) * 40 + (lane >> 4) * 8];
#pragma unroll
                for (int mt = 0; mt < MTW; ++mt)
                    acc[mt][nt] = __builtin_amdgcn_mfma_f32_16x16x32_bf16(a[mt], bb, acc[mt][nt], 0, 0, 0);
            }
        }
    }

    const int xl = lane & 15, rg = lane >> 4;
#pragma unroll
    for (int mt = 0; mt < MTW; ++mt) {
        int t = (mb * nWm + wm) * MTW + mt;
        int m0 = t * 16;
        if (t >= MT || m0 >= Cout) continue;
#pragma unroll
        for (int nt = 0; nt < NTW; ++nt) {
            int xx2 = x0 + (wn * NTW + nt) * 16 + xl;
            short pk[4];
#pragma unroll
            for (int j = 0; j < 4; ++j) {
                int o = m0 + rg * 4 + j;
                float rv = acc[mt][nt][j] + bias[o];
                if (ACT) rv = (rv >= 0.f) ? rv : 0.1f * rv;
                pk[j] = f2bf(rv);
            }
            if (QMAJ) {
                int blk = (y * WW + xx2) >> 4;
                size_t rec = (size_t)b * (HW / 16) + blk;
                if (t < 18) {                            // dy/dx channels
                    int q0 = (m0 + rg * 4) >> 1;         // pair index (even)
                    unsigned d0 = ((unsigned)(unsigned short)pk[1] << 16) | (unsigned short)pk[0];
                    unsigned d1 = ((unsigned)(unsigned short)pk[3] << 16) | (unsigned short)pk[2];
                    outp[(rec * 144 + q0) * 16 + xl]     = d0;
                    outp[(rec * 144 + q0 + 1) * 16 + xl] = d1;
                } else {                                 // mask channels
                    int c0 = m0 + rg * 4 - 288;
#pragma unroll
                    for (int j = 0; j < 4; ++j)
                        outm[(rec * 144 + c0 + j) * 16 + xl] = pk[j];
                }
            } else {
                *(uint2*)(out + ((size_t)b * HW + (size_t)y * WW + xx2) * (size_t)Cout
                          + m0 + rg * 4) = *(const uint2*)pk;
            }
        }
    }
}

// ---------------------------------------------------------------------------
// Fused DCNv2 v11 (unchanged from round 16): paired-column gathers +
// block-local offset layout.
// ---------------------------------------------------------------------------
__global__ __launch_bounds__(256) void dcn_k(
    const short* __restrict__ xt, const float* __restrict__ flow,
    const unsigned* __restrict__ o4p, const short* __restrict__ o4m,
    const short* __restrict__ wtp, const float* __restrict__ bias,
    float* __restrict__ out)
{
    __shared__ alignas(16) short s[16 * SSTR];
    const int tid = threadIdx.x;
    const int b = blockIdx.z, y = blockIdx.y, xb = blockIdx.x * 16;
    const size_t hw = (size_t)HW;
    constexpr float L2E = 1.4426950408889634f;

    const int lane = tid & 63, wv = tid >> 6;
    const int p = tid & 15;
    const int dg = tid >> 4;                 // 0..15
    const int xp = xb + p;
    const size_t pix = (size_t)y * WW + xp;
    const short* xg = xt + ((size_t)b * 16 + dg) * hw * 4;   // dg-major slice
    const float fl0 = flow[((size_t)b * 2 + 0) * hw + pix];
    const float fl1 = flow[((size_t)b * 2 + 1) * hw + pix];

    const size_t rec = (size_t)b * (HW / 16) + ((size_t)y * 8 + blockIdx.x);
    const unsigned* pd = o4p + (rec * 144 + 9 * dg) * 16 + p;   // stride 16/item
    const short* pm = o4m + (rec * 144 + 9 * dg) * 16 + p;
    short* sp = &s[p * SSTR + dg * 36];

#pragma unroll
    for (int it = 0; it < 9; ++it) {
        unsigned dyx = pd[it * 16];
        float omk = bf2f(pm[it * 16]);
        float ody = bflo(dyx), odx = bfhi(dyx);
        float tdy = 1.f - 2.f * __builtin_amdgcn_rcpf(__builtin_amdgcn_exp2f(2.f * L2E * ody) + 1.f);
        float tdx = 1.f - 2.f * __builtin_amdgcn_rcpf(__builtin_amdgcn_exp2f(2.f * L2E * odx) + 1.f);
        float m   = __builtin_amdgcn_rcpf(1.f + __builtin_amdgcn_exp2f(-L2E * omk));

        float py = 10.f * tdy + fl1 + (float)(y  - 1 + it / 3);
        float px = 10.f * tdx + fl0 + (float)(xp - 1 + it % 3);
        float fy = floorf(py), fx = floorf(px);
        int iy0 = (int)fy, ix0 = (int)fx;
        float wy1 = py - fy, wx1 = px - fx;
        float wy0 = 1.f - wy1, wx0 = 1.f - wx1;
        int iy1 = iy0 + 1, ix1 = ix0 + 1;
        bool vy0 = (iy0 >= 0) & (iy0 < HH), vy1 = (iy1 >= 0) & (iy1 < HH);
        bool vx0 = (ix0 >= 0) & (ix0 < WW), vx1 = (ix1 >= 0) & (ix1 < WW);
        float w00 = (vy0 & vx0) ? wy0 * wx0 : 0.f;
        float w01 = (vy0 & vx1) ? wy0 * wx1 : 0.f;
        float w10 = (vy1 & vx0) ? wy1 * wx0 : 0.f;
        float w11 = (vy1 & vx1) ? wy1 * wx1 : 0.f;
        int cy0 = min(max(iy0, 0), HH - 1), cy1 = min(max(iy1, 0), HH - 1);

        // paired-column gather: one 16B load per row covers both corners
        int bx = min(max(ix0, 0), WW - 2);
        int cx0 = min(max(ix0, 0), WW - 1);
        int cx1 = min(max(ix0 + 1, 0), WW - 1);
        bool s0 = (cx0 != bx);               // 0 normally, 1 at right clamp
        bool s1 = (cx1 != bx);               // 1 normally, 0 at left clamp
        uint4a r0 = *(const uint4a*)(xg + (size_t)(cy0 * WW + bx) * 4);
        uint4a r1 = *(const uint4a*)(xg + (size_t)(cy1 * WW + bx) * 4);
        unsigned d00x = s0 ? r0.z : r0.x, d00y = s0 ? r0.w : r0.y;
        unsigned d01x = s1 ? r0.z : r0.x, d01y = s1 ? r0.w : r0.y;
        unsigned d10x = s0 ? r1.z : r1.x, d10y = s0 ? r1.w : r1.y;
        unsigned d11x = s1 ? r1.z : r1.x, d11y = s1 ? r1.w : r1.y;

        float a0 = w00 * bflo(d00x) + w01 * bflo(d01x) + w10 * bflo(d10x) + w11 * bflo(d11x);
        float a1 = w00 * bfhi(d00x) + w01 * bfhi(d01x) + w10 * bfhi(d10x) + w11 * bfhi(d11x);
        float a2 = w00 * bflo(d00y) + w01 * bflo(d01y) + w10 * bflo(d10y) + w11 * bflo(d11y);
        float a3 = w00 * bfhi(d00y) + w01 * bfhi(d01y) + w10 * bfhi(d10y) + w11 * bfhi(d11y);

        uint2 t;
        t.x = ((unsigned)(unsigned short)f2bf(a1 * m) << 16) | (unsigned short)f2bf(a0 * m);
        t.y = ((unsigned)(unsigned short)f2bf(a3 * m) << 16) | (unsigned short)f2bf(a2 * m);
        *(uint2*)&sp[it * 4] = t;            // immediate store: no live arrays
    }
    __syncthreads();

    f32x4 acc = {};
#pragma unroll
    for (int kc = 0; kc < 18; ++kc) {
        bf16x8 a = *(const bf16x8*)(wtp + ((size_t)(kc * 4 + wv) * 64 + lane) * 8);
        bf16x8 bb = *(const bf16x8*)&s[(lane & 15) * SSTR + kc * 32 + (lane >> 4) * 8];
        acc = __builtin_amdgcn_mfma_f32_16x16x32_bf16(a, bb, acc, 0, 0, 0);
    }

    const int xl = lane & 15, rg = lane >> 4;
#pragma unroll
    for (int j = 0; j < 4; ++j) {
        int o = wv * 16 + rg * 4 + j;
        out[((size_t)(b * 64 + o) * HH + y) * WW + xb + xl] = acc[j] + bias[o];
    }
}

// ---------------------------------------------------------------------------
extern "C" void kernel_launch(void* const* d_in, const int* in_sizes, int n_in,
                              void* d_out, int out_size, void* d_ws, size_t ws_size,
                              hipStream_t stream)
{
    const float* x    = (const float*)d_in[0];
    const float* xfw  = (const float*)d_in[1];
    const float* xcur = (const float*)d_in[2];
    const float* flow = (const float*)d_in[3];
    const float* w1   = (const float*)d_in[4];
    const float* b1   = (const float*)d_in[5];
    const float* w2   = (const float*)d_in[6];
    const float* b2   = (const float*)d_in[7];
    const float* w3   = (const float*)d_in[8];
    const float* b3   = (const float*)d_in[9];
    const float* w4   = (const float*)d_in[10];
    const float* b4   = (const float*)d_in[11];
    const float* wt   = (const float*)d_in[12];
    const float* bs   = (const float*)d_in[13];

    const size_t hw = (size_t)HW;
    // out4 region: pairs (B*1024*144*16 dwords) then masks (same count shorts)
    unsigned* o4p = (unsigned*)d_ws;
    short*    o4m = (short*)(o4p + (size_t)BH * (hw / 16) * 144 * 16);
    short* h1   = (short*)d_ws + (size_t)BH * hw * 432;   // after pairs+masks
    short* h2   = h1 + (size_t)BH * hw * 64;
    short* cc   = h2 + (size_t)BH * hw * 64;              // B*HW*144 (+pad)
    short* xt   = cc + (size_t)BH * hw * 144 + 256;       // B*16*HW*4 dg-major
    short* wp1  = xt + (size_t)BH * hw * 64 + 256;
    short* wp2  = wp1 + (size_t)180 * 512;
    short* wp3  = wp2 + (size_t)72 * 512;
    short* wp4  = wp3 + (size_t)72 * 512;
    short* wtp  = wp4 + (size_t)486 * 512;

    RepackArgs ra;
    ra.w[0] = w1; ra.w[1] = w2; ra.w[2] = w3; ra.w[3] = w4; ra.w[4] = wt;
    ra.dst[0] = wp1; ra.dst[1] = wp2; ra.dst[2] = wp3; ra.dst[3] = wp4; ra.dst[4] = wtp;
    int tot[5] = {11520, 4608, 4608, 31104, 4608};
    ra.off[0] = 0;
    for (int i = 0; i < 5; ++i) ra.off[i + 1] = ra.off[i] + tot[i];
    repack_all_k<<<(ra.off[5] + 255) / 256, 256, 0, stream>>>(ra);

    prep_k<<<dim3(HW / 256, 1, 2 * BH), 256, 0, stream>>>(xfw, xcur, flow, x, cc, xt);

    dim3 blk(256);
    conv_mfma_k<144, 5, true,  2, 2, false><<<dim3(2, 128, BH),     blk, 0, stream>>>(
        cc, wp1, b1, h1, nullptr, nullptr, 64, 1, 4);
    conv_mfma_k<64,  2, true,  2, 2, false><<<dim3(2, 128, BH),     blk, 0, stream>>>(
        h1, wp2, b2, h2, nullptr, nullptr, 64, 1, 4);
    conv_mfma_k<64,  2, true,  2, 2, false><<<dim3(2, 128, BH),     blk, 0, stream>>>(
        h2, wp3, b3, h1, nullptr, nullptr, 64, 1, 4);
    conv_mfma_k<64,  2, false, 4, 4, true ><<<dim3(2, 128, BH * 2), blk, 0, stream>>>(
        h1, wp4, b4, nullptr, o4p, o4m, 432, 2, 27);

    dcn_k<<<dim3(WW / 16, HH, BH), blk, 0, stream>>>(xt, flow, o4p, o4m, wtp, bs, (float*)d_out);
}

// Round 18
// 191.830 us; speedup vs baseline: 1.0333x; 1.0333x over previous
//
#include <hip/hip_runtime.h>
#include <math.h>
#include <type_traits>

#define BH 4
#define HH 128
#define WW 128
#define HW (HH * WW)
#define SSTR 600   // dcn LDS row stride in shorts (1200B)

typedef __attribute__((ext_vector_type(8))) short bf16x8;
typedef __attribute__((ext_vector_type(4))) float f32x4;
typedef unsigned uint4a __attribute__((ext_vector_type(4), aligned(4)));

__device__ inline short f2bf(float f) {
    union { float f; unsigned u; } x; x.f = f;
    unsigned r = x.u + 0x7fff + ((x.u >> 16) & 1);   // RNE
    return (short)(r >> 16);
}
__device__ inline float bf2f(short h) {
    union { unsigned u; float f; } x; x.u = ((unsigned)(unsigned short)h) << 16;
    return x.f;
}
__device__ inline float bflo(unsigned u) {
    union { unsigned u; float f; } x; x.u = u << 16; return x.f;
}
__device__ inline float bfhi(unsigned u) {
    union { unsigned u; float f; } x; x.u = u & 0xffff0000u; return x.f;
}
__device__ inline float h2f(unsigned short u) {
    _Float16 h; __builtin_memcpy(&h, &u, 2); return (float)h;
}
__device__ inline unsigned short f2h(float f) {
    _Float16 h = (_Float16)f; unsigned short s; __builtin_memcpy(&s, &h, 2); return s;
}

// ---------------------------------------------------------------------------
// Unified weight repack: jobs 0-3 generic conv weights, job 4 = deform wt.
// ---------------------------------------------------------------------------
struct RepackArgs {
    const float* w[5];
    short* dst[5];
    int off[6];
};

__device__ inline void repack_generic(const float* w, short* dst, int g,
                                      int M, int Cin, int T, int MT)
{
    int lane = g & 63;
    int f = g >> 6;
    int mt = f % MT;
    int kt = f / MT;
    int tap = kt % T;
    int kc = kt / T;
    int m = mt * 16 + (lane & 15);
    int ic0 = kc * 32 + (lane >> 4) * 8;
    short v[8];
#pragma unroll
    for (int i = 0; i < 8; ++i) {
        int ic = ic0 + i;
        float x = (m < M && ic < Cin) ? w[((size_t)m * Cin + ic) * T + tap] : 0.f;
        v[i] = f2bf(x);
    }
    *(bf16x8*)(dst + (size_t)g * 8) = *(const bf16x8*)v;
}

__global__ __launch_bounds__(256) void repack_all_k(RepackArgs a)
{
    int g = blockIdx.x * 256 + threadIdx.x;
    if (g < a.off[1]) {
        repack_generic(a.w[0], a.dst[0], g - a.off[0], 64, 130, 9, 4);
    } else if (g < a.off[2]) {
        repack_generic(a.w[1], a.dst[1], g - a.off[1], 64, 64, 9, 4);
    } else if (g < a.off[3]) {
        repack_generic(a.w[2], a.dst[2], g - a.off[2], 64, 64, 9, 4);
    } else if (g < a.off[4]) {
        repack_generic(a.w[3], a.dst[3], g - a.off[3], 432, 64, 9, 27);
    } else if (g < a.off[5]) {
        int gg = g - a.off[4];
        int lane = gg & 63;
        int f = gg >> 6;
        int mt = f & 3, kc = f >> 2;
        int m = mt * 16 + (lane & 15);
        int ck0 = kc * 32 + (lane >> 4) * 8;
        short v[8];
#pragma unroll
        for (int i = 0; i < 8; ++i) {
            int ck = ck0 + i;                     // < 576
            int dg = ck / 36, rem = ck % 36;
            int k = rem >> 2, cg = rem & 3;
            int c = dg * 4 + cg;
            v[i] = f2bf(a.w[4][((size_t)m * 64 + c) * 9 + k]);
        }
        *(bf16x8*)(a.dst[4] + (size_t)gg * 8) = *(const bf16x8*)v;
    }
}

// ---------------------------------------------------------------------------
// Merged prep: z<BH -> build NHWC concat buffer [B][HW][144];
//              z>=BH -> x NCHW f32 -> dg-major bf16 xt[B][16][HW][4].
// ---------------------------------------------------------------------------
__global__ __launch_bounds__(256) void prep_k(
    const float* __restrict__ xfw, const float* __restrict__ xcur,
    const float* __restrict__ flow, const float* __restrict__ x,
    short* __restrict__ cc, short* __restrict__ xt)
{
    int tid = threadIdx.x;
    int z = blockIdx.z;
    int px = blockIdx.x * 256 + tid;
    if (z < BH) {
        int b = z;
        const float* s0 = xfw + (size_t)b * 64 * HW + px;
        const float* s1 = xcur + (size_t)b * 64 * HW + px;
        const float* s2 = flow + (size_t)b * 2 * HW + px;
        short v[144];
#pragma unroll
        for (int c = 0; c < 64; ++c) v[c] = f2bf(s0[(size_t)c * HW]);
#pragma unroll
        for (int c = 0; c < 64; ++c) v[64 + c] = f2bf(s1[(size_t)c * HW]);
        v[128] = f2bf(s2[0]);
        v[129] = f2bf(s2[HW]);
#pragma unroll
        for (int c = 130; c < 144; ++c) v[c] = 0;
        short* dst = cc + ((size_t)b * HW + px) * 144;
#pragma unroll
        for (int q = 0; q < 18; ++q)
            *(bf16x8*)(dst + q * 8) = *(const bf16x8*)&v[q * 8];
    } else {
        int b = z - BH;
        const float* src = x + (size_t)b * 64 * HW + px;
        short v[64];
#pragma unroll
        for (int c = 0; c < 64; ++c) v[c] = f2bf(src[(size_t)c * HW]);
        short* dstb = xt + (size_t)b * 16 * HW * 4 + (size_t)px * 4;
#pragma unroll
        for (int d = 0; d < 16; ++d)
            *(uint2*)(dstb + (size_t)d * HW * 4) = *(const uint2*)&v[d * 4];
    }
}

// ---------------------------------------------------------------------------
// Implicit-GEMM 3x3 conv, NHWC bf16 in, mfma_f32_16x16x32_bf16.
// Round-10/16 structure: 256 thr / 4 waves; tile M = 64*MTW, N=64 px/row.
// QMAJ (conv4): epilogue applies the DCN offset transform from the F32
// accumulator and stores block-local F16 pair/mask layout:
//   pairs[b][pix/16][144 q][16 p]  (dword = (dy,dx) f16 pair; dy incl +flow1,
//                                   dx incl +flow0; value = 10*tanh(acc)+flow)
//   masks[b][pix/16][144 c][16 p]  (f16 sigmoid)
// ---------------------------------------------------------------------------
template<int CSTR, int KC, bool ACT, int MTW, bool QMAJ>
__global__ __launch_bounds__(256) void conv_mfma_k(
    const short* __restrict__ in, const short* __restrict__ wp,
    const float* __restrict__ bias, const float* __restrict__ flow,
    short* __restrict__ out,
    unsigned* __restrict__ outp, short* __restrict__ outm,
    int Cout, int MB, int MT)
{
    __shared__ alignas(16) short X[3 * 66 * 40];
    const int tid = threadIdx.x;
    const int lane = tid & 63, wv = tid >> 6;
    const int x0 = blockIdx.x * 64, y = blockIdx.y;
    const int zb = blockIdx.z;
    const int b = zb / MB, mb = zb % MB;
    constexpr float L2E = 1.4426950408889634f;

    int mtg[MTW];
#pragma unroll
    for (int mt = 0; mt < MTW; ++mt) {
        int t = (mb * 4 + wv) * MTW + mt;
        mtg[mt] = (t < MT) ? t : MT - 1;      // clamp loads; stores masked
    }

    const int r = tid / 66, c = tid - r * 66;
    const int yy = y + r - 1, xx = x0 + c - 1;
    const bool inb = (tid < 198) && (yy >= 0 && yy < HH && xx >= 0 && xx < WW);
    const short* srcp = in + ((size_t)b * HW + (size_t)yy * WW + xx) * CSTR;
    short* dstp = &X[(r * 66 + c) * 40];

    f32x4 acc[MTW][4] = {};

    for (int kc = 0; kc < KC; ++kc) {
        __syncthreads();
        if (tid < 198) {
            if (inb) {
                const short* s0 = srcp + kc * 32;
#pragma unroll
                for (int g = 0; g < 4; ++g)
                    *(bf16x8*)&dstp[g * 8] = *(const bf16x8*)&s0[g * 8];
            } else {
                bf16x8 z = {};
#pragma unroll
                for (int g = 0; g < 4; ++g) *(bf16x8*)&dstp[g * 8] = z;
            }
        }
        __syncthreads();
#pragma unroll
        for (int tap = 0; tap < 9; ++tap) {
            const int dy = tap / 3, dx = tap - dy * 3;
            bf16x8 a[MTW];
#pragma unroll
            for (int mt = 0; mt < MTW; ++mt)
                a[mt] = *(const bf16x8*)(wp + (((size_t)(kc * 9 + tap) * MT + mtg[mt]) * 64 + lane) * 8);
#pragma unroll
            for (int nt = 0; nt < 4; ++nt) {
                int cc2 = nt * 16 + (lane & 15) + dx;
                bf16x8 bb = *(const bf16x8*)&X[(dy * 66 + cc2) * 40 + (lane >> 4) * 8];
#pragma unroll
                for (int mt = 0; mt < MTW; ++mt)
                    acc[mt][nt] = __builtin_amdgcn_mfma_f32_16x16x32_bf16(a[mt], bb, acc[mt][nt], 0, 0, 0);
            }
        }
    }

    const int xl = lane & 15, rg = lane >> 4;
#pragma unroll
    for (int mt = 0; mt < MTW; ++mt) {
        int t = (mb * 4 + wv) * MTW + mt;
        int m0 = t * 16;
        if (t >= MT || m0 >= Cout) continue;
#pragma unroll
        for (int nt = 0; nt < 4; ++nt) {
            int xx2 = x0 + nt * 16 + xl;
            if (QMAJ) {
                int blk = (y * WW + xx2) >> 4;
                size_t rec = (size_t)b * (HW / 16) + blk;
                size_t pix2 = (size_t)y * WW + xx2;
                if (t < 18) {                            // dy/dx channels
                    float fl0 = flow[((size_t)b * 2 + 0) * HW + pix2];
                    float fl1 = flow[((size_t)b * 2 + 1) * HW + pix2];
                    unsigned short q[4];
#pragma unroll
                    for (int j = 0; j < 4; ++j) {
                        int o = m0 + rg * 4 + j;
                        float rv = acc[mt][nt][j] + bias[o];
                        float th = 1.f - 2.f * __builtin_amdgcn_rcpf(
                            __builtin_amdgcn_exp2f(2.f * L2E * rv) + 1.f);
                        float v = 10.f * th + ((o & 1) ? fl0 : fl1);
                        q[j] = f2h(v);
                    }
                    int q0 = (m0 + rg * 4) >> 1;         // pair index (even)
                    outp[(rec * 144 + q0) * 16 + xl]     = ((unsigned)q[1] << 16) | q[0];
                    outp[(rec * 144 + q0 + 1) * 16 + xl] = ((unsigned)q[3] << 16) | q[2];
                } else {                                 // mask channels
                    int c0 = m0 + rg * 4 - 288;
#pragma unroll
                    for (int j = 0; j < 4; ++j) {
                        float rv = acc[mt][nt][j] + bias[m0 + rg * 4 + j];
                        float mv = __builtin_amdgcn_rcpf(
                            1.f + __builtin_amdgcn_exp2f(-L2E * rv));
                        outm[(rec * 144 + c0 + j) * 16 + xl] = (short)f2h(mv);
                    }
                }
            } else {
                short pk[4];
#pragma unroll
                for (int j = 0; j < 4; ++j) {
                    int o = m0 + rg * 4 + j;
                    float rv = acc[mt][nt][j] + bias[o];
                    if (ACT) rv = (rv >= 0.f) ? rv : 0.1f * rv;
                    pk[j] = f2bf(rv);
                }
                *(uint2*)(out + ((size_t)b * HW + (size_t)y * WW + xx2) * (size_t)Cout
                          + m0 + rg * 4) = *(const uint2*)pk;
            }
        }
    }
}

// ---------------------------------------------------------------------------
// Fused DCNv2 v12: offsets/masks arrive PRE-TRANSFORMED in f16 (block-local
// layout) -> phase 1 has ZERO transcendentals and no flow loads:
// load f16 pair -> cvt -> floor -> paired-column gather -> blend.
// ---------------------------------------------------------------------------
__global__ __launch_bounds__(256) void dcn_k(
    const short* __restrict__ xt,
    const unsigned* __restrict__ o4p, const short* __restrict__ o4m,
    const short* __restrict__ wtp, const float* __restrict__ bias,
    float* __restrict__ out)
{
    __shared__ alignas(16) short s[16 * SSTR];
    const int tid = threadIdx.x;
    const int b = blockIdx.z, y = blockIdx.y, xb = blockIdx.x * 16;
    const size_t hw = (size_t)HW;

    const int lane = tid & 63, wv = tid >> 6;
    const int p = tid & 15;
    const int dg = tid >> 4;                 // 0..15
    const int xp = xb + p;
    const short* xg = xt + ((size_t)b * 16 + dg) * hw * 4;   // dg-major slice

    const size_t rec = (size_t)b * (HW / 16) + ((size_t)y * 8 + blockIdx.x);
    const unsigned* pd = o4p + (rec * 144 + 9 * dg) * 16 + p;   // stride 16/item
    const short* pm = o4m + (rec * 144 + 9 * dg) * 16 + p;
    short* sp = &s[p * SSTR + dg * 36];

#pragma unroll
    for (int it = 0; it < 9; ++it) {
        unsigned dyx = pd[it * 16];
        float m = h2f((unsigned short)pm[it * 16]);

        float py = h2f((unsigned short)(dyx & 0xffff)) + (float)(y  - 1 + it / 3);
        float px = h2f((unsigned short)(dyx >> 16))    + (float)(xp - 1 + it % 3);
        float fy = floorf(py), fx = floorf(px);
        int iy0 = (int)fy, ix0 = (int)fx;
        float wy1 = py - fy, wx1 = px - fx;
        float wy0 = 1.f - wy1, wx0 = 1.f - wx1;
        int iy1 = iy0 + 1, ix1 = ix0 + 1;
        bool vy0 = (iy0 >= 0) & (iy0 < HH), vy1 = (iy1 >= 0) & (iy1 < HH);
        bool vx0 = (ix0 >= 0) & (ix0 < WW), vx1 = (ix1 >= 0) & (ix1 < WW);
        float w00 = (vy0 & vx0) ? wy0 * wx0 : 0.f;
        float w01 = (vy0 & vx1) ? wy0 * wx1 : 0.f;
        float w10 = (vy1 & vx0) ? wy1 * wx0 : 0.f;
        float w11 = (vy1 & vx1) ? wy1 * wx1 : 0.f;
        int cy0 = min(max(iy0, 0), HH - 1), cy1 = min(max(iy1, 0), HH - 1);

        // paired-column gather: one 16B load per row covers both corners
        int bx = min(max(ix0, 0), WW - 2);
        int cx0 = min(max(ix0, 0), WW - 1);
        int cx1 = min(max(ix0 + 1, 0), WW - 1);
        bool s0 = (cx0 != bx);               // 0 normally, 1 at right clamp
        bool s1 = (cx1 != bx);               // 1 normally, 0 at left clamp
        uint4a r0 = *(const uint4a*)(xg + (size_t)(cy0 * WW + bx) * 4);
        uint4a r1 = *(const uint4a*)(xg + (size_t)(cy1 * WW + bx) * 4);
        unsigned d00x = s0 ? r0.z : r0.x, d00y = s0 ? r0.w : r0.y;
        unsigned d01x = s1 ? r0.z : r0.x, d01y = s1 ? r0.w : r0.y;
        unsigned d10x = s0 ? r1.z : r1.x, d10y = s0 ? r1.w : r1.y;
        unsigned d11x = s1 ? r1.z : r1.x, d11y = s1 ? r1.w : r1.y;

        float a0 = w00 * bflo(d00x) + w01 * bflo(d01x) + w10 * bflo(d10x) + w11 * bflo(d11x);
        float a1 = w00 * bfhi(d00x) + w01 * bfhi(d01x) + w10 * bfhi(d10x) + w11 * bfhi(d11x);
        float a2 = w00 * bflo(d00y) + w01 * bflo(d01y) + w10 * bflo(d10y) + w11 * bflo(d11y);
        float a3 = w00 * bfhi(d00y) + w01 * bfhi(d01y) + w10 * bfhi(d10y) + w11 * bfhi(d11y);

        uint2 t;
        t.x = ((unsigned)(unsigned short)f2bf(a1 * m) << 16) | (unsigned short)f2bf(a0 * m);
        t.y = ((unsigned)(unsigned short)f2bf(a3 * m) << 16) | (unsigned short)f2bf(a2 * m);
        *(uint2*)&sp[it * 4] = t;            // immediate store: no live arrays
    }
    __syncthreads();

    f32x4 acc = {};
#pragma unroll
    for (int kc = 0; kc < 18; ++kc) {
        bf16x8 a = *(const bf16x8*)(wtp + ((size_t)(kc * 4 + wv) * 64 + lane) * 8);
        bf16x8 bb = *(const bf16x8*)&s[(lane & 15) * SSTR + kc * 32 + (lane >> 4) * 8];
        acc = __builtin_amdgcn_mfma_f32_16x16x32_bf16(a, bb, acc, 0, 0, 0);
    }

    const int xl = lane & 15, rg = lane >> 4;
#pragma unroll
    for (int j = 0; j < 4; ++j) {
        int o = wv * 16 + rg * 4 + j;
        out[((size_t)(b * 64 + o) * HH + y) * WW + xb + xl] = acc[j] + bias[o];
    }
}

// ---------------------------------------------------------------------------
extern "C" void kernel_launch(void* const* d_in, const int* in_sizes, int n_in,
                              void* d_out, int out_size, void* d_ws, size_t ws_size,
                              hipStream_t stream)
{
    const float* x    = (const float*)d_in[0];
    const float* xfw  = (const float*)d_in[1];
    const float* xcur = (const float*)d_in[2];
    const float* flow = (const float*)d_in[3];
    const float* w1   = (const float*)d_in[4];
    const float* b1   = (const float*)d_in[5];
    const float* w2   = (const float*)d_in[6];
    const float* b2   = (const float*)d_in[7];
    const float* w3   = (const float*)d_in[8];
    const float* b3   = (const float*)d_in[9];
    const float* w4   = (const float*)d_in[10];
    const float* b4   = (const float*)d_in[11];
    const float* wt   = (const float*)d_in[12];
    const float* bs   = (const float*)d_in[13];

    const size_t hw = (size_t)HW;
    // out4 region: pairs (B*1024*144*16 dwords) then masks (same count shorts)
    unsigned* o4p = (unsigned*)d_ws;
    short*    o4m = (short*)(o4p + (size_t)BH * (hw / 16) * 144 * 16);
    short* h1   = (short*)d_ws + (size_t)BH * hw * 432;   // after pairs+masks
    short* h2   = h1 + (size_t)BH * hw * 64;
    short* cc   = h2 + (size_t)BH * hw * 64;              // B*HW*144 (+pad)
    short* xt   = cc + (size_t)BH * hw * 144 + 256;       // B*16*HW*4 dg-major
    short* wp1  = xt + (size_t)BH * hw * 64 + 256;
    short* wp2  = wp1 + (size_t)180 * 512;
    short* wp3  = wp2 + (size_t)72 * 512;
    short* wp4  = wp3 + (size_t)72 * 512;
    short* wtp  = wp4 + (size_t)486 * 512;

    RepackArgs ra;
    ra.w[0] = w1; ra.w[1] = w2; ra.w[2] = w3; ra.w[3] = w4; ra.w[4] = wt;
    ra.dst[0] = wp1; ra.dst[1] = wp2; ra.dst[2] = wp3; ra.dst[3] = wp4; ra.dst[4] = wtp;
    int tot[5] = {11520, 4608, 4608, 31104, 4608};
    ra.off[0] = 0;
    for (int i = 0; i < 5; ++i) ra.off[i + 1] = ra.off[i] + tot[i];
    repack_all_k<<<(ra.off[5] + 255) / 256, 256, 0, stream>>>(ra);

    prep_k<<<dim3(HW / 256, 1, 2 * BH), 256, 0, stream>>>(xfw, xcur, flow, x, cc, xt);

    dim3 blk(256);
    conv_mfma_k<144, 5, true,  1, false><<<dim3(2, 128, BH),     blk, 0, stream>>>(
        cc, wp1, b1, nullptr, h1, nullptr, nullptr, 64, 1, 4);
    conv_mfma_k<64,  2, true,  1, false><<<dim3(2, 128, BH),     blk, 0, stream>>>(
        h1, wp2, b2, nullptr, h2, nullptr, nullptr, 64, 1, 4);
    conv_mfma_k<64,  2, true,  1, false><<<dim3(2, 128, BH),     blk, 0, stream>>>(
        h2, wp3, b3, nullptr, h1, nullptr, nullptr, 64, 1, 4);
    conv_mfma_k<64,  2, false, 4, true ><<<dim3(2, 128, BH * 2), blk, 0, stream>>>(
        h1, wp4, b4, flow, nullptr, o4p, o4m, 432, 2, 27);

    dcn_k<<<dim3(WW / 16, HH, BH), blk, 0, stream>>>(xt, o4p, o4m, wtp, bs, (float*)d_out);
}